// Round 9
// baseline (51.136 us; speedup 1.0000x reference)
//
#include <hip/hip_runtime.h>

namespace {

constexpr int T   = 16384;
constexpr int B   = 8;
constexpr int C4  = 64;            // 256 fp32 channels as 64 float4
constexpr int SUB = 16;            // timesteps per wave
constexpr int NROWS = SUB + 10;    // 26 rows per chunk (halo 5 each side)
constexpr int WAVES_PER_BLOCK = 4; // block = 256 threads
constexpr int BLOCK_T = SUB * WAVES_PER_BLOCK; // 64 timesteps per block
constexpr int CHUNKS = T / BLOCK_T;            // 256 chunks per batch

typedef float vfloat4 __attribute__((ext_vector_type(4)));  // native clang vector

__device__ __forceinline__ void stnt(float4* p, float4 v) {
    vfloat4 nv = {v.x, v.y, v.z, v.w};
    __builtin_nontemporal_store(nv, (vfloat4*)p);
}

// Volatile asm load: strict program order among loads, dst pinned live until
// consumed -> compiler cannot re-serialize the prefetch (R2/R8 failure mode).
__device__ __forceinline__ vfloat4 ld_asm(const float4* p) {
    vfloat4 d;
    asm volatile("global_load_dwordx4 %0, %1, off"
                 : "=v"(d)
                 : "v"(p)
                 : "memory");
    return d;
}

__device__ __forceinline__ void consume(const vfloat4* __restrict__ r,
                                        float4* __restrict__ ob) {
    constexpr float INV = 1.0f / 11.0f;
    vfloat4 s = {0.f, 0.f, 0.f, 0.f};
    #pragma unroll
    for (int i = 0; i < 11; ++i) s += r[i];
    vfloat4 o = s * INV;
    stnt(ob, float4{o.x, o.y, o.z, o.w});
    #pragma unroll
    for (int i = 1; i < SUB; ++i) {
        s += r[i + 10] - r[i - 1];
        o = s * INV;
        stnt(ob + (size_t)i * C4, float4{o.x, o.y, o.z, o.w});
    }
}

__device__ __forceinline__ void run_fast(const float4* __restrict__ xb,
                                         float4* __restrict__ ob, int t0) {
    vfloat4 r[NROWS];
    #pragma unroll
    for (int i = 0; i < NROWS; ++i) {
        r[i] = ld_asm(xb + (size_t)(t0 - 5 + i) * C4);   // 26 loads in flight
    }
    asm volatile("s_waitcnt vmcnt(0)" ::: "memory");
    __builtin_amdgcn_sched_barrier(0);                   // rule #18 fence
    consume(r, ob);
}

__device__ __forceinline__ void run_guard(const float4* __restrict__ xb,
                                          float4* __restrict__ ob, int t0) {
    vfloat4 r[NROWS];
    #pragma unroll
    for (int i = 0; i < NROWS; ++i) {
        const int tt = t0 - 5 + i;
        if (tt >= 0 && tt < T) {
            const float4 v = xb[(size_t)tt * C4];
            r[i] = vfloat4{v.x, v.y, v.z, v.w};
        } else {
            r[i] = vfloat4{0.f, 0.f, 0.f, 0.f};
        }
    }
    consume(r, ob);
}

__global__ __launch_bounds__(256, 2) void runavg_kernel(const float4* __restrict__ x,
                                                        float4* __restrict__ out) {
    const int lane = threadIdx.x & 63;   // channel-group (float4) index
    const int wid  = threadIdx.x >> 6;   // wave within block -> time sub-chunk
    const int b  = blockIdx.x / CHUNKS;
    const int t0 = (blockIdx.x % CHUNKS) * BLOCK_T + wid * SUB;

    const float4* __restrict__ xb = x   + (size_t)b * T * C4 + lane;
    float4* __restrict__       ob = out + ((size_t)b * T + t0) * C4 + lane;

    if (t0 >= 5 && t0 + SUB + 5 <= T) {
        run_fast(xb, ob, t0);
    } else {
        run_guard(xb, ob, t0);
    }
}

} // namespace

extern "C" void kernel_launch(void* const* d_in, const int* in_sizes, int n_in,
                              void* d_out, int out_size, void* d_ws, size_t ws_size,
                              hipStream_t stream) {
    const float4* x = (const float4*)d_in[0];
    float4* out = (float4*)d_out;
    const int grid = B * CHUNKS;  // 2048 blocks
    runavg_kernel<<<grid, 256, 0, stream>>>(x, out);
}

// Round 10
// 42.880 us; speedup vs baseline: 1.1926x; 1.1926x over previous
//
#include <hip/hip_runtime.h>

namespace {

constexpr int T   = 16384;
constexpr int B   = 8;
constexpr int C4  = 64;            // 256 fp32 channels as 64 float4
constexpr int SUB = 8;             // timesteps per wave
constexpr int NROWS = SUB + 10;    // 18 rows per chunk (halo 5 each side)
constexpr int WAVES_PER_BLOCK = 4; // block = 256 threads
constexpr int BLOCK_T = SUB * WAVES_PER_BLOCK; // 32 timesteps per block
constexpr int CHUNKS = T / BLOCK_T;            // 512 chunks per batch
constexpr int NBLK   = B * CHUNKS;             // 4096 blocks total
constexpr int NXCD   = 8;
constexpr int CPX    = NBLK / NXCD;            // 512 — exact, bijective swizzle

template <bool GUARD>
__device__ __forceinline__ float4 ldx(const float4* __restrict__ xb, int tt) {
    if (GUARD) {
        if (tt < 0 || tt >= T) return float4{0.f, 0.f, 0.f, 0.f};
    }
    return xb[(size_t)tt * C4];
}

template <bool GUARD>
__device__ __forceinline__ void run_chunk(const float4* __restrict__ xb,
                                          float4* __restrict__ ob, int t0) {
    constexpr float INV = 1.0f / 11.0f;

    float4 r[NROWS];
    #pragma unroll
    for (int i = 0; i < NROWS; ++i) {
        r[i] = ldx<GUARD>(xb, t0 - 5 + i);
    }
    __builtin_amdgcn_sched_barrier(0);

    float4 s = {0.f, 0.f, 0.f, 0.f};
    #pragma unroll
    for (int i = 0; i < 11; ++i) {
        s.x += r[i].x; s.y += r[i].y; s.z += r[i].z; s.w += r[i].w;
    }
    float4 o;
    o.x = s.x * INV; o.y = s.y * INV; o.z = s.z * INV; o.w = s.w * INV;
    ob[0] = o;                                  // regular store (A/B vs nt)

    #pragma unroll
    for (int i = 1; i < SUB; ++i) {
        const float4 a = r[i + 10];
        const float4 d = r[i - 1];
        s.x += a.x - d.x; s.y += a.y - d.y; s.z += a.z - d.z; s.w += a.w - d.w;
        o.x = s.x * INV; o.y = s.y * INV; o.z = s.z * INV; o.w = s.w * INV;
        ob[(size_t)i * C4] = o;
    }
}

__global__ __launch_bounds__(256) void runavg_kernel(const float4* __restrict__ x,
                                                     float4* __restrict__ out) {
    const int lane = threadIdx.x & 63;   // channel-group (float4) index
    const int wid  = threadIdx.x >> 6;   // wave within block -> time sub-chunk

    // XCD-chunked bijective swizzle (T1): consecutive hardware blocks
    // round-robin XCDs; remap so each XCD owns a contiguous time-span ->
    // neighbor-chunk halo re-reads hit own-XCD L2.
    const int bid  = blockIdx.x;
    const int work = (bid % NXCD) * CPX + bid / NXCD;

    const int b   = work / CHUNKS;
    const int t0b = (work % CHUNKS) * BLOCK_T;
    const int t0  = t0b + wid * SUB;

    const float4* __restrict__ xb = x   + (size_t)b * T * C4 + lane;
    float4* __restrict__       ob = out + ((size_t)b * T + t0) * C4 + lane;

    if (t0 >= 5 && t0 + SUB + 5 <= T) {
        run_chunk<false>(xb, ob, t0);
    } else {
        run_chunk<true>(xb, ob, t0);
    }
}

} // namespace

extern "C" void kernel_launch(void* const* d_in, const int* in_sizes, int n_in,
                              void* d_out, int out_size, void* d_ws, size_t ws_size,
                              hipStream_t stream) {
    const float4* x = (const float4*)d_in[0];
    float4* out = (float4*)d_out;
    runavg_kernel<<<NBLK, 256, 0, stream>>>(x, out);
}